// Round 1
// baseline (99.433 us; speedup 1.0000x reference)
//
#include <hip/hip_runtime.h>
#include <math.h>

// ---------------------------------------------------------------------------
// DetectionLoss: 3-level anchor-based detection loss (obj BCE w/ hard-negative
// mining, cls CE, smooth-L1 loc), exact match of the JAX reference semantics.
//
// ws layout (bytes):
//   [0     ) int   npos[96]
//   [1024  ) float sum_bce_pos[96]
//   [2048  ) float sum_ce[96]
//   [3072  ) float sum_sl1[96]
//   [4096  ) float tot[3]      (obj, cls, loc accumulators)
//   [8192  ) uint  keys[2064384]  order-mapped BCE of negatives (0 = not neg)
// total ~8.27 MB
// ---------------------------------------------------------------------------

#define NLVL 3
#define BATCH 32
#define NBOX 20

__device__ __forceinline__ float softplusf(float x) {
    // jax.nn.softplus = logaddexp(x, 0) = max(x,0) + log1p(exp(-|x|))
    return fmaxf(x, 0.0f) + log1pf(expf(-fabsf(x)));
}
__device__ __forceinline__ unsigned mapf(float f) {
    unsigned u = __float_as_uint(f);
    return (u & 0x80000000u) ? ~u : (u | 0x80000000u);
}
__device__ __forceinline__ float unmapf(unsigned k) {
    unsigned u = (k & 0x80000000u) ? (k & 0x7FFFFFFFu) : ~k;
    return __uint_as_float(u);
}

// Level key-array base offsets (elements)
#define KEY_OFS0 0
#define KEY_OFS1 1572864   // 32 * 128*128*3
#define KEY_OFS2 1966080   // + 32 * 64*64*3
#define NKEYS    2064384   // + 32 * 32*32*3

// ---------------------------------------------------------------------------
// Kernel 1: per-anchor assignment + BCE + pos-side loss accumulation.
// One thread = one pixel; loops s = 0..2 anchor scales.
// Blocks: level0: 32 img * 64 blk, level1: 32*16, level2: 32*4  => 2688
// ---------------------------------------------------------------------------
__global__ __launch_bounds__(256) void k_assign(
    const float* __restrict__ pred0, const float* __restrict__ pred1,
    const float* __restrict__ pred2,
    const float* __restrict__ tboxes, const int* __restrict__ tlabels,
    int* __restrict__ nposA, float* __restrict__ sumbce,
    float* __restrict__ sumce, float* __restrict__ sumsl1,
    unsigned* __restrict__ keys)
{
    int bid = blockIdx.x;
    int l, rel;
    if (bid < 2048)      { l = 0; rel = bid; }
    else if (bid < 2560) { l = 1; rel = bid - 2048; }
    else                 { l = 2; rel = bid - 2560; }

    int W, stride, bpi, keyofs;
    const float* pred;
    if (l == 0)      { W = 128; stride = 8;  bpi = 64; pred = pred0; keyofs = KEY_OFS0; }
    else if (l == 1) { W = 64;  stride = 16; bpi = 16; pred = pred1; keyofs = KEY_OFS1; }
    else             { W = 32;  stride = 32; bpi = 4;  pred = pred2; keyofs = KEY_OFS2; }
    int HW = W * W;
    int b  = rel / bpi;
    int pb = rel % bpi;
    int li = l * BATCH + b;
    int t  = threadIdx.x;
    int p  = pb * 256 + t;            // pixel index (HW is a multiple of 256... L2: 1024 = 4*256 OK)

    __shared__ float sbb[NBOX * 4];
    __shared__ float sarea[NBOX];
    __shared__ int   slab[NBOX];
    if (t < NBOX * 4) sbb[t] = tboxes[b * NBOX * 4 + t];
    if (t >= 128 && t < 128 + NBOX) slab[t - 128] = tlabels[b * NBOX + (t - 128)];
    __syncthreads();
    if (t < NBOX) sarea[t] = (sbb[4 * t + 2] - sbb[4 * t]) * (sbb[4 * t + 3] - sbb[4 * t + 1]);
    __syncthreads();

    int h = p / W, w = p % W;
    float cx = (w + 0.5f) * (float)stride;
    float cy = (h + 0.5f) * (float)stride;
    const float* pbase = pred + (size_t)b * 24 * HW;

    for (int s = 0; s < 3; ++s) {
        float scale = (s == 0) ? 1.0f : ((s == 1) ? 1.5f : 2.0f);
        float half = scale * (float)stride * 0.75f;
        float ax0 = cx - half, ay0 = cy - half, ax1 = cx + half, ay1 = cy + half;
        float areaA = (ax1 - ax0) * (ay1 - ay0);

        float best = -1.0f; int idx = 0;
        #pragma unroll
        for (int m = 0; m < NBOX; ++m) {
            float bx0 = sbb[4 * m], by0 = sbb[4 * m + 1], bx1 = sbb[4 * m + 2], by1 = sbb[4 * m + 3];
            float ix = fminf(ax1, bx1) - fmaxf(ax0, bx0);
            float iy = fminf(ay1, by1) - fmaxf(ay0, by0);
            ix = fmaxf(ix, 0.0f); iy = fmaxf(iy, 0.0f);
            float inter = ix * iy;
            float uni = areaA + sarea[m] - inter;
            float iou = inter / fmaxf(uni, 1e-8f);
            if (iou > best) { best = iou; idx = m; }
        }
        bool pos = (best >= 0.5f);
        bool neg = (best < 0.4f);

        float obj = pbase[(size_t)(s * 8 + 4) * HW + p];
        float sp  = softplusf(obj);
        float bce = pos ? (sp - obj) : sp;

        keys[(size_t)keyofs + (size_t)b * HW * 3 + (size_t)p * 3 + s] = neg ? mapf(bce) : 0u;

        if (pos) {
            atomicAdd(&nposA[li], 1);
            atomicAdd(&sumbce[li], bce);
            // classification CE
            float c0 = pbase[(size_t)(s * 8 + 5) * HW + p];
            float c1 = pbase[(size_t)(s * 8 + 6) * HW + p];
            float c2 = pbase[(size_t)(s * 8 + 7) * HW + p];
            float mx = fmaxf(c0, fmaxf(c1, c2));
            float lse = mx + logf(expf(c0 - mx) + expf(c1 - mx) + expf(c2 - mx));
            int lab = slab[idx] - 1;
            float cl = (lab == 0) ? c0 : ((lab == 1) ? c1 : c2);
            atomicAdd(&sumce[li], lse - cl);
            // smooth-L1 loc
            float mb0 = sbb[4 * idx], mb1 = sbb[4 * idx + 1], mb2 = sbb[4 * idx + 2], mb3 = sbb[4 * idx + 3];
            float ssum = 0.0f;
            {
                float d = pbase[(size_t)(s * 8 + 0) * HW + p] - mb0;
                float ad = fabsf(d); ssum += (ad < 1.0f) ? 0.5f * d * d : ad - 0.5f;
            }
            {
                float d = pbase[(size_t)(s * 8 + 1) * HW + p] - mb1;
                float ad = fabsf(d); ssum += (ad < 1.0f) ? 0.5f * d * d : ad - 0.5f;
            }
            {
                float d = pbase[(size_t)(s * 8 + 2) * HW + p] - mb2;
                float ad = fabsf(d); ssum += (ad < 1.0f) ? 0.5f * d * d : ad - 0.5f;
            }
            {
                float d = pbase[(size_t)(s * 8 + 3) * HW + p] - mb3;
                float ad = fabsf(d); ssum += (ad < 1.0f) ? 0.5f * d * d : ad - 0.5f;
            }
            atomicAdd(&sumsl1[li], ssum);
        }
    }
}

// ---------------------------------------------------------------------------
// Kernel 2: per-(level,image) exact top-K negative selection via radix select
// on order-mapped float keys, then final per-(level,image) losses -> atomics.
// 96 blocks x 256 threads.
// ---------------------------------------------------------------------------
__global__ __launch_bounds__(256) void k_select(
    const int* __restrict__ nposA, const float* __restrict__ sumbce,
    const float* __restrict__ sumce, const float* __restrict__ sumsl1,
    const unsigned* __restrict__ keys, float* __restrict__ tot)
{
    int li = blockIdx.x;
    int np = nposA[li];
    if (np == 0) return;   // all three losses are exactly 0 for this (level,image)

    int l = li >> 5, b = li & 31;
    int HW, keyofs;
    if (l == 0)      { HW = 16384; keyofs = KEY_OFS0; }
    else if (l == 1) { HW = 4096;  keyofs = KEY_OFS1; }
    else             { HW = 1024;  keyofs = KEY_OFS2; }
    int N = HW * 3;
    const unsigned* kk = keys + keyofs + (size_t)b * N;

    __shared__ int hist[256];
    __shared__ int suf[256];
    __shared__ int s_bin, s_want, s_K;
    int t = threadIdx.x;

    unsigned prefix = 0;
    int K = -1, want = 0;

    for (int pass = 0; pass < 4; ++pass) {
        hist[t] = 0;
        __syncthreads();
        int shift = 24 - 8 * pass;
        if (pass == 0) {
            for (int i = t; i < N; i += 256) {
                unsigned key = kk[i];
                atomicAdd(&hist[key >> 24], 1);
            }
        } else {
            for (int i = t; i < N; i += 256) {
                unsigned key = kk[i];
                if ((key >> (shift + 8)) == prefix) atomicAdd(&hist[(key >> shift) & 255u], 1);
            }
        }
        __syncthreads();
        suf[t] = hist[t];
        __syncthreads();
        for (int off = 1; off < 256; off <<= 1) {
            int add = (t + off < 256) ? suf[t + off] : 0;
            __syncthreads();
            suf[t] += add;
            __syncthreads();
        }
        if (pass == 0) {
            if (t == 0) {
                int negc = suf[128];              // all neg keys have top bit set
                s_K = min(3 * np, negc);
            }
            __syncthreads();
            K = s_K;
            want = K;
            if (K == 0) break;                    // uniform
        }
        // boundary bin: unique t with suf[t] >= want > suf[t+1]
        if (suf[t] >= want && (t == 255 || suf[t + 1] < want)) {
            s_bin = t;
            s_want = want - ((t < 255) ? suf[t + 1] : 0);
        }
        __syncthreads();
        prefix = (prefix << 8) | (unsigned)s_bin;
        want = s_want;
        __syncthreads();
    }

    __shared__ float partial[4];
    float negsum = 0.0f;
    if (K > 0) {
        unsigned T = prefix;   // exact K-th largest key
        float lsum = 0.0f;
        for (int i = t; i < N; i += 256) {
            unsigned key = kk[i];
            if (key > T) lsum += unmapf(key);
        }
        for (int off = 32; off > 0; off >>= 1) lsum += __shfl_down(lsum, off, 64);
        if ((t & 63) == 0) partial[t >> 6] = lsum;
        __syncthreads();
        if (t == 0)
            negsum = partial[0] + partial[1] + partial[2] + partial[3]
                   + (float)want * unmapf(T);     // ties at threshold: identical values
    }

    if (t == 0) {
        int nsel = np + K;
        float obj_l = (nsel > 0) ? (sumbce[li] + negsum) / (float)nsel : 0.0f;
        float cls_l = sumce[li] / (float)np;
        float loc_l = sumsl1[li] / (float)(4 * np);
        atomicAdd(&tot[0], obj_l);
        atomicAdd(&tot[1], cls_l);
        atomicAdd(&tot[2], loc_l);
    }
}

// ---------------------------------------------------------------------------
// Kernel 3: finalize
// ---------------------------------------------------------------------------
__global__ void k_final(const float* __restrict__ tot, float* __restrict__ out)
{
    if (threadIdx.x == 0) {
        float o = tot[0] * (1.0f / BATCH);
        float c = tot[1] * (1.0f / BATCH);
        float l = tot[2] * (1.0f / BATCH);
        out[0] = o; out[1] = c; out[2] = l; out[3] = o + c + 2.0f * l;
    }
}

extern "C" void kernel_launch(void* const* d_in, const int* in_sizes, int n_in,
                              void* d_out, int out_size, void* d_ws, size_t ws_size,
                              hipStream_t stream) {
    const float* pred0  = (const float*)d_in[0];
    const float* pred1  = (const float*)d_in[1];
    const float* pred2  = (const float*)d_in[2];
    // d_in[3..5] = anchor arrays (recomputed on the fly, exactly representable)
    const float* tboxes = (const float*)d_in[6];
    const int*   tlabels= (const int*)d_in[7];

    char* ws = (char*)d_ws;
    int*      nposA  = (int*)ws;
    float*    sumbce = (float*)(ws + 1024);
    float*    sumce  = (float*)(ws + 2048);
    float*    sumsl1 = (float*)(ws + 3072);
    float*    tot    = (float*)(ws + 4096);
    unsigned* keys   = (unsigned*)(ws + 8192);

    hipMemsetAsync(d_ws, 0, 8192, stream);

    hipLaunchKernelGGL(k_assign, dim3(2688), dim3(256), 0, stream,
                       pred0, pred1, pred2, tboxes, tlabels,
                       nposA, sumbce, sumce, sumsl1, keys);
    hipLaunchKernelGGL(k_select, dim3(96), dim3(256), 0, stream,
                       nposA, sumbce, sumce, sumsl1, keys, tot);
    hipLaunchKernelGGL(k_final, dim3(1), dim3(64), 0, stream, tot, (float*)d_out);
}

// Round 2
// 64.120 us; speedup vs baseline: 1.5507x; 1.5507x over previous
//
#include <hip/hip_runtime.h>
#include <math.h>

// ---------------------------------------------------------------------------
// DetectionLoss — exact-semantics anchor loss with fast-math VALU paths.
//
// ws layout (bytes):
//   [0    ) int   npos[96]
//   [1024 ) float sum_bce_pos[96]
//   [2048 ) float sum_ce[96]
//   [3072 ) float sum_sl1[96]
//   [4096 ) float tot[3]
//   [4112 ) int   dcount
//   [8192 ) uint  keys[2064384]   order-mapped BCE of negatives (0 = not neg)
// ---------------------------------------------------------------------------

#define BATCH 32
#define NBOX 20

#define KEY_OFS0 0
#define KEY_OFS1 1572864   // 32 * 128*128*3
#define KEY_OFS2 1966080   // + 32 * 64*64*3
#define NKEYS    2064384   // + 32 * 32*32*3

__device__ __forceinline__ unsigned mapf(float f) {
    unsigned u = __float_as_uint(f);
    return (u & 0x80000000u) ? ~u : (u | 0x80000000u);
}
__device__ __forceinline__ float unmapf(unsigned k) {
    unsigned u = (k & 0x80000000u) ? (k & 0x7FFFFFFFu) : ~k;
    return __uint_as_float(u);
}

// ---------------------------------------------------------------------------
// Kernel 1: per-anchor assignment + BCE + pos-side losses.
// One thread = one pixel, 3 anchor scales in registers, boxes outer loop.
// ---------------------------------------------------------------------------
__global__ __launch_bounds__(256) void k_assign(
    const float* __restrict__ pred0, const float* __restrict__ pred1,
    const float* __restrict__ pred2,
    const float* __restrict__ tboxes, const int* __restrict__ tlabels,
    int* __restrict__ nposA, float* __restrict__ sumbce,
    float* __restrict__ sumce, float* __restrict__ sumsl1,
    unsigned* __restrict__ keys)
{
    int bid = blockIdx.x;
    int l, rel;
    if (bid < 2048)      { l = 0; rel = bid; }
    else if (bid < 2560) { l = 1; rel = bid - 2048; }
    else                 { l = 2; rel = bid - 2560; }

    int lw, stridei, bpi, keyofs;
    const float* pred;
    if (l == 0)      { lw = 7; stridei = 8;  bpi = 64; pred = pred0; keyofs = KEY_OFS0; }
    else if (l == 1) { lw = 6; stridei = 16; bpi = 16; pred = pred1; keyofs = KEY_OFS1; }
    else             { lw = 5; stridei = 32; bpi = 4;  pred = pred2; keyofs = KEY_OFS2; }
    int W  = 1 << lw;
    int HW = W * W;
    int b  = rel / bpi;
    int pb = rel - b * bpi;
    int li = l * BATCH + b;
    int t  = threadIdx.x;
    int p  = pb * 256 + t;

    __shared__ float sbb[NBOX * 4];
    __shared__ float sarea[NBOX];
    __shared__ int   slab[NBOX];
    if (t < 80) sbb[t] = tboxes[b * 80 + t];
    if (t >= 128 && t < 148) slab[t - 128] = tlabels[b * 20 + (t - 128)];
    __syncthreads();
    if (t < 20) sarea[t] = (sbb[4 * t + 2] - sbb[4 * t]) * (sbb[4 * t + 3] - sbb[4 * t + 1]);
    __syncthreads();

    float fs = (float)stridei;
    float cx = ((p & (W - 1)) + 0.5f) * fs;
    float cy = ((p >> lw)     + 0.5f) * fs;
    float h0 = 0.75f * fs, h1 = 1.125f * fs, h2 = 1.5f * fs;
    float a0 = (2.f*h0)*(2.f*h0), a1 = (2.f*h1)*(2.f*h1), a2 = (2.f*h2)*(2.f*h2);

    float best0 = -1.f, best1 = -1.f, best2 = -1.f;
    int   id0 = 0, id1 = 0, id2 = 0;

    #pragma unroll
    for (int m = 0; m < NBOX; ++m) {
        float bx0 = sbb[4*m], by0 = sbb[4*m+1], bx1 = sbb[4*m+2], by1 = sbb[4*m+3];
        float ab  = sarea[m];
        float dx0 = cx - bx0, dx1 = bx1 - cx;
        float dy0 = cy - by0, dy1 = by1 - cy;
        {
            float ix = fminf(h0, dx0) + fminf(h0, dx1);
            float iy = fminf(h0, dy0) + fminf(h0, dy1);
            ix = fmaxf(ix, 0.f); iy = fmaxf(iy, 0.f);
            float inter = ix * iy;
            float uni   = a0 + ab - inter;
            float iou   = inter * __builtin_amdgcn_rcpf(fmaxf(uni, 1e-8f));
            if (iou > best0) { best0 = iou; id0 = m; }
        }
        {
            float ix = fminf(h1, dx0) + fminf(h1, dx1);
            float iy = fminf(h1, dy0) + fminf(h1, dy1);
            ix = fmaxf(ix, 0.f); iy = fmaxf(iy, 0.f);
            float inter = ix * iy;
            float uni   = a1 + ab - inter;
            float iou   = inter * __builtin_amdgcn_rcpf(fmaxf(uni, 1e-8f));
            if (iou > best1) { best1 = iou; id1 = m; }
        }
        {
            float ix = fminf(h2, dx0) + fminf(h2, dx1);
            float iy = fminf(h2, dy0) + fminf(h2, dy1);
            ix = fmaxf(ix, 0.f); iy = fmaxf(iy, 0.f);
            float inter = ix * iy;
            float uni   = a2 + ab - inter;
            float iou   = inter * __builtin_amdgcn_rcpf(fmaxf(uni, 1e-8f));
            if (iou > best2) { best2 = iou; id2 = m; }
        }
    }

    const float* pbase = pred + (size_t)b * 24 * HW;
    unsigned* kbase = keys + keyofs + (size_t)b * HW * 3;

    auto do_scale = [&](int s, float best, int idx) {
        bool pos = best >= 0.5f;
        bool neg = best < 0.4f;
        float obj = pbase[(size_t)(s * 8 + 4) * HW + p];
        float sp  = fmaxf(obj, 0.f) + __logf(1.f + __expf(-fabsf(obj)));
        float bce = pos ? sp - obj : sp;
        kbase[s * HW + p] = neg ? mapf(bce) : 0u;   // coalesced per-s plane
        if (pos) {
            atomicAdd(&nposA[li], 1);
            atomicAdd(&sumbce[li], bce);
            float c0 = pbase[(size_t)(s * 8 + 5) * HW + p];
            float c1 = pbase[(size_t)(s * 8 + 6) * HW + p];
            float c2 = pbase[(size_t)(s * 8 + 7) * HW + p];
            float mx = fmaxf(c0, fmaxf(c1, c2));
            float lse = mx + __logf(__expf(c0 - mx) + __expf(c1 - mx) + __expf(c2 - mx));
            int lab = slab[idx] - 1;
            float cl = (lab == 0) ? c0 : ((lab == 1) ? c1 : c2);
            atomicAdd(&sumce[li], lse - cl);
            float ssum = 0.f;
            #pragma unroll
            for (int q = 0; q < 4; ++q) {
                float d  = pbase[(size_t)(s * 8 + q) * HW + p] - sbb[4 * idx + q];
                float ad = fabsf(d);
                ssum += (ad < 1.f) ? 0.5f * d * d : ad - 0.5f;
            }
            atomicAdd(&sumsl1[li], ssum);
        }
    };
    do_scale(0, best0, id0);
    do_scale(1, best1, id1);
    do_scale(2, best2, id2);
}

// ---------------------------------------------------------------------------
// Kernel 2: per-(level,image) exact top-K negative radix select + finalize.
// 96 blocks x 1024 threads. 4 key sweeps total (sum fused into pass 3).
// Last finished block writes d_out (device-scope counter).
// ---------------------------------------------------------------------------
__global__ __launch_bounds__(1024) void k_select(
    const int* __restrict__ nposA, const float* __restrict__ sumbce,
    const float* __restrict__ sumce, const float* __restrict__ sumsl1,
    const unsigned* __restrict__ keys, float* __restrict__ tot,
    int* __restrict__ dcount, float* __restrict__ out)
{
    int li = blockIdx.x;
    int t  = threadIdx.x;
    int np = nposA[li];

    __shared__ int   lhist[256];
    __shared__ float lsumf[256];
    __shared__ int   sufi[257];
    __shared__ float suff[257];
    __shared__ int   wtot[4];
    __shared__ float wtotf[4];
    __shared__ int   s_bin, s_want, s_K;
    __shared__ float s_extra;
    __shared__ float redbuf[16];

    if (np > 0) {
        int l = li >> 5, b = li & 31;
        int HW, keyofs;
        if (l == 0)      { HW = 16384; keyofs = KEY_OFS0; }
        else if (l == 1) { HW = 4096;  keyofs = KEY_OFS1; }
        else             { HW = 1024;  keyofs = KEY_OFS2; }
        int N  = HW * 3;
        int N4 = N >> 2;
        const uint4* kk4 = reinterpret_cast<const uint4*>(keys + keyofs + (size_t)b * N);

        unsigned prefix = 0;
        int K = 0, want = 0;
        float negsum = 0.f;
        int lane = t & 63;

        for (int pass = 0; pass < 4; ++pass) {
            if (t < 256) { lhist[t] = 0; lsumf[t] = 0.f; }
            __syncthreads();

            float big = 0.f;
            if (pass == 0) {
                for (int i = t; i < N4; i += 1024) {
                    uint4 k4 = kk4[i];
                    atomicAdd(&lhist[k4.x >> 24], 1);
                    atomicAdd(&lhist[k4.y >> 24], 1);
                    atomicAdd(&lhist[k4.z >> 24], 1);
                    atomicAdd(&lhist[k4.w >> 24], 1);
                }
            } else if (pass < 3) {
                int shift = 24 - 8 * pass;
                for (int i = t; i < N4; i += 1024) {
                    uint4 k4 = kk4[i];
                    unsigned kA[4] = {k4.x, k4.y, k4.z, k4.w};
                    #pragma unroll
                    for (int j = 0; j < 4; ++j)
                        if ((kA[j] >> (shift + 8)) == prefix)
                            atomicAdd(&lhist[(kA[j] >> shift) & 255u], 1);
                }
            } else {
                for (int i = t; i < N4; i += 1024) {
                    uint4 k4 = kk4[i];
                    unsigned kA[4] = {k4.x, k4.y, k4.z, k4.w};
                    #pragma unroll
                    for (int j = 0; j < 4; ++j) {
                        unsigned key = kA[j];
                        unsigned top = key >> 8;
                        if (top > prefix) big += unmapf(key);
                        else if (top == prefix) {
                            atomicAdd(&lhist[key & 255u], 1);
                            atomicAdd(&lsumf[key & 255u], unmapf(key));
                        }
                    }
                }
                for (int off = 32; off > 0; off >>= 1) big += __shfl_down(big, off, 64);
                if (lane == 0) redbuf[t >> 6] = big;
            }
            __syncthreads();
            if (pass == 3 && t == 0) {
                float sb = 0.f;
                for (int j = 0; j < 16; ++j) sb += redbuf[j];
                s_extra = sb;
            }

            // suffix scan of lhist (and lsumf on pass 3) using threads 0..255
            int v = 0; float vf = 0.f;
            if (t < 256) {
                v = lhist[t]; vf = lsumf[t];
                for (int off = 1; off < 64; off <<= 1) {
                    int   o  = __shfl_down(v,  off, 64);
                    float of = __shfl_down(vf, off, 64);
                    if (lane + off < 64) { v += o; vf += of; }
                }
                if (lane == 0) { wtot[t >> 6] = v; wtotf[t >> 6] = vf; }
            }
            __syncthreads();
            if (t < 256) {
                int w = t >> 6;
                int add = 0; float addf = 0.f;
                for (int j = w + 1; j < 4; ++j) { add += wtot[j]; addf += wtotf[j]; }
                sufi[t] = v + add;
                suff[t] = vf + addf;
            }
            if (t == 0) { sufi[256] = 0; suff[256] = 0.f; }
            __syncthreads();

            if (pass == 0) {
                if (t == 0) s_K = min(3 * np, sufi[128]);
                __syncthreads();
                K = s_K; want = K;
                if (K == 0) break;
            }
            if (t < 256 && sufi[t] >= want && sufi[t + 1] < want) {
                s_bin  = t;
                s_want = want - sufi[t + 1];
            }
            __syncthreads();
            prefix = (prefix << 8) | (unsigned)s_bin;
            want   = s_want;
            __syncthreads();
        }

        if (t == 0) {
            if (K > 0) {
                int b0 = (int)(prefix & 255u);
                negsum = s_extra + suff[b0 + 1] + (float)want * unmapf(prefix);
            }
            int nsel = np + K;
            float obj_l = (sumbce[li] + negsum) / (float)nsel;
            float cls_l = sumce[li] / (float)np;
            float loc_l = sumsl1[li] / (float)(4 * np);
            atomicAdd(&tot[0], obj_l);
            atomicAdd(&tot[1], cls_l);
            atomicAdd(&tot[2], loc_l);
        }
    }

    // fused finalize: last block to arrive writes the output
    __threadfence();
    if (t == 0) {
        int prev = atomicAdd(dcount, 1);
        if (prev == 95) {
            __threadfence();
            float o  = atomicAdd(&tot[0], 0.f) * (1.f / BATCH);
            float c  = atomicAdd(&tot[1], 0.f) * (1.f / BATCH);
            float lo = atomicAdd(&tot[2], 0.f) * (1.f / BATCH);
            out[0] = o; out[1] = c; out[2] = lo; out[3] = o + c + 2.f * lo;
        }
    }
}

extern "C" void kernel_launch(void* const* d_in, const int* in_sizes, int n_in,
                              void* d_out, int out_size, void* d_ws, size_t ws_size,
                              hipStream_t stream) {
    const float* pred0   = (const float*)d_in[0];
    const float* pred1   = (const float*)d_in[1];
    const float* pred2   = (const float*)d_in[2];
    const float* tboxes  = (const float*)d_in[6];
    const int*   tlabels = (const int*)d_in[7];

    char* ws = (char*)d_ws;
    int*      nposA  = (int*)ws;
    float*    sumbce = (float*)(ws + 1024);
    float*    sumce  = (float*)(ws + 2048);
    float*    sumsl1 = (float*)(ws + 3072);
    float*    tot    = (float*)(ws + 4096);
    int*      dcount = (int*)(ws + 4112);
    unsigned* keys   = (unsigned*)(ws + 8192);

    hipMemsetAsync(d_ws, 0, 8192, stream);

    hipLaunchKernelGGL(k_assign, dim3(2688), dim3(256), 0, stream,
                       pred0, pred1, pred2, tboxes, tlabels,
                       nposA, sumbce, sumce, sumsl1, keys);
    hipLaunchKernelGGL(k_select, dim3(96), dim3(1024), 0, stream,
                       nposA, sumbce, sumce, sumsl1, keys, tot, dcount,
                       (float*)d_out);
}

// Round 4
// 60.710 us; speedup vs baseline: 1.6378x; 1.0562x over previous
//
#include <hip/hip_runtime.h>
#include <math.h>

// ---------------------------------------------------------------------------
// DetectionLoss — exact-semantics anchor loss.
//
// ws layout (bytes):
//   [0    ) int   npos[96]
//   [1024 ) float sum_bce_pos[96]
//   [2048 ) float sum_ce[96]
//   [3072 ) float sum_sl1[96]
//   [4096 ) float tot[3]
//   [4112 ) int   dcount
//   [8192 ) uint  keys[2064384]   order-mapped BCE of negatives (0 = not neg)
// ---------------------------------------------------------------------------

#define BATCH 32
#define NBOX 20

#define KEY_OFS0 0
#define KEY_OFS1 1572864   // 32 * 128*128*3
#define KEY_OFS2 1966080   // + 32 * 64*64*3

__device__ __forceinline__ unsigned mapf(float f) {
    unsigned u = __float_as_uint(f);
    return (u & 0x80000000u) ? ~u : (u | 0x80000000u);
}
__device__ __forceinline__ float unmapf(unsigned k) {
    unsigned u = (k & 0x80000000u) ? (k & 0x7FFFFFFFu) : ~k;
    return __uint_as_float(u);
}

// ---------------------------------------------------------------------------
// Kernel 0: zero the small stats region (replaces 39us runtime fill kernel).
// NOTE: grid-stride — region is 1040 words but block is 1024 threads.
// ---------------------------------------------------------------------------
__global__ __launch_bounds__(1024) void k_init(int* __restrict__ ws)
{
    for (int i = threadIdx.x; i < 1040; i += 1024) ws[i] = 0;
}

// ---------------------------------------------------------------------------
// Kernel 1: per-anchor assignment + BCE + pos-side losses.
// One thread = one pixel, 3 anchor scales in registers, boxes outer loop.
// Division-free IoU argmax: best kept as rational (bi, bu).
// ---------------------------------------------------------------------------
__global__ __launch_bounds__(256) void k_assign(
    const float* __restrict__ pred0, const float* __restrict__ pred1,
    const float* __restrict__ pred2,
    const float* __restrict__ tboxes, const int* __restrict__ tlabels,
    int* __restrict__ nposA, float* __restrict__ sumbce,
    float* __restrict__ sumce, float* __restrict__ sumsl1,
    unsigned* __restrict__ keys)
{
    int bid = blockIdx.x;
    int l, rel;
    if (bid < 2048)      { l = 0; rel = bid; }
    else if (bid < 2560) { l = 1; rel = bid - 2048; }
    else                 { l = 2; rel = bid - 2560; }

    int lw, stridei, bpi, keyofs;
    const float* pred;
    if (l == 0)      { lw = 7; stridei = 8;  bpi = 64; pred = pred0; keyofs = KEY_OFS0; }
    else if (l == 1) { lw = 6; stridei = 16; bpi = 16; pred = pred1; keyofs = KEY_OFS1; }
    else             { lw = 5; stridei = 32; bpi = 4;  pred = pred2; keyofs = KEY_OFS2; }
    int W  = 1 << lw;
    int HW = W * W;
    int b  = rel / bpi;
    int pb = rel - b * bpi;
    int li = l * BATCH + b;
    int t  = threadIdx.x;
    int p  = pb * 256 + t;

    __shared__ float sbb[NBOX * 4];
    __shared__ float sarea[NBOX];
    __shared__ int   slab[NBOX];
    if (t < 80) sbb[t] = tboxes[b * 80 + t];
    if (t >= 128 && t < 148) slab[t - 128] = tlabels[b * 20 + (t - 128)];
    __syncthreads();
    if (t < 20) sarea[t] = (sbb[4 * t + 2] - sbb[4 * t]) * (sbb[4 * t + 3] - sbb[4 * t + 1]);
    __syncthreads();

    float fs = (float)stridei;
    float cx = ((p & (W - 1)) + 0.5f) * fs;
    float cy = ((p >> lw)     + 0.5f) * fs;
    float h0 = 0.75f * fs, h1 = 1.125f * fs, h2 = 1.5f * fs;
    float a0 = (2.f*h0)*(2.f*h0), a1 = (2.f*h1)*(2.f*h1), a2 = (2.f*h2)*(2.f*h2);

    // rational best: bi/bu, init -1/1 (first candidate always wins, incl. 0)
    float bi0 = -1.f, bu0 = 1.f, bi1 = -1.f, bu1 = 1.f, bi2 = -1.f, bu2 = 1.f;
    int   id0 = 0, id1 = 0, id2 = 0;

    #pragma unroll
    for (int m = 0; m < NBOX; ++m) {
        float bx0 = sbb[4*m], by0 = sbb[4*m+1], bx1 = sbb[4*m+2], by1 = sbb[4*m+3];
        float ab  = sarea[m];
        float dx0 = cx - bx0, dx1 = bx1 - cx;
        float dy0 = cy - by0, dy1 = by1 - cy;
        {
            float ix = fminf(h0, dx0) + fminf(h0, dx1);
            float iy = fminf(h0, dy0) + fminf(h0, dy1);
            ix = fmaxf(ix, 0.f); iy = fmaxf(iy, 0.f);
            float inter = ix * iy;
            float uni   = fmaxf(a0 + ab - inter, 1e-8f);
            if (inter * bu0 > bi0 * uni) { bi0 = inter; bu0 = uni; id0 = m; }
        }
        {
            float ix = fminf(h1, dx0) + fminf(h1, dx1);
            float iy = fminf(h1, dy0) + fminf(h1, dy1);
            ix = fmaxf(ix, 0.f); iy = fmaxf(iy, 0.f);
            float inter = ix * iy;
            float uni   = fmaxf(a1 + ab - inter, 1e-8f);
            if (inter * bu1 > bi1 * uni) { bi1 = inter; bu1 = uni; id1 = m; }
        }
        {
            float ix = fminf(h2, dx0) + fminf(h2, dx1);
            float iy = fminf(h2, dy0) + fminf(h2, dy1);
            ix = fmaxf(ix, 0.f); iy = fmaxf(iy, 0.f);
            float inter = ix * iy;
            float uni   = fmaxf(a2 + ab - inter, 1e-8f);
            if (inter * bu2 > bi2 * uni) { bi2 = inter; bu2 = uni; id2 = m; }
        }
    }

    const float* pbase = pred + (size_t)b * 24 * HW;
    unsigned* kbase = keys + keyofs + (size_t)b * HW * 3;

    auto do_scale = [&](int s, float bi, float bu, int idx) {
        bool pos = bi >= 0.5f * bu;
        bool neg = bi < 0.4f * bu;
        float obj = pbase[(size_t)(s * 8 + 4) * HW + p];
        float sp  = fmaxf(obj, 0.f) + __logf(1.f + __expf(-fabsf(obj)));
        float bce = pos ? sp - obj : sp;
        kbase[s * HW + p] = neg ? mapf(bce) : 0u;   // coalesced per-s plane
        if (pos) {
            atomicAdd(&nposA[li], 1);
            atomicAdd(&sumbce[li], bce);
            float c0 = pbase[(size_t)(s * 8 + 5) * HW + p];
            float c1 = pbase[(size_t)(s * 8 + 6) * HW + p];
            float c2 = pbase[(size_t)(s * 8 + 7) * HW + p];
            float mx = fmaxf(c0, fmaxf(c1, c2));
            float lse = mx + __logf(__expf(c0 - mx) + __expf(c1 - mx) + __expf(c2 - mx));
            int lab = slab[idx] - 1;
            float cl = (lab == 0) ? c0 : ((lab == 1) ? c1 : c2);
            atomicAdd(&sumce[li], lse - cl);
            float ssum = 0.f;
            #pragma unroll
            for (int q = 0; q < 4; ++q) {
                float d  = pbase[(size_t)(s * 8 + q) * HW + p] - sbb[4 * idx + q];
                float ad = fabsf(d);
                ssum += (ad < 1.f) ? 0.5f * d * d : ad - 0.5f;
            }
            atomicAdd(&sumsl1[li], ssum);
        }
    };
    do_scale(0, bi0, bu0, id0);
    do_scale(1, bi1, bu1, id1);
    do_scale(2, bi2, bu2, id2);
}

// ---------------------------------------------------------------------------
// Kernel 2: per-(level,image) exact top-K negative radix select + finalize.
// 96 blocks x 1024 threads. 4 key sweeps total (sum fused into pass 3).
// Last finished block writes d_out (device-scope counter).
// ---------------------------------------------------------------------------
__global__ __launch_bounds__(1024) void k_select(
    const int* __restrict__ nposA, const float* __restrict__ sumbce,
    const float* __restrict__ sumce, const float* __restrict__ sumsl1,
    const unsigned* __restrict__ keys, float* __restrict__ tot,
    int* __restrict__ dcount, float* __restrict__ out)
{
    int li = blockIdx.x;
    int t  = threadIdx.x;
    int np = nposA[li];

    __shared__ int   lhist[256];
    __shared__ float lsumf[256];
    __shared__ int   sufi[257];
    __shared__ float suff[257];
    __shared__ int   wtot[4];
    __shared__ float wtotf[4];
    __shared__ int   s_bin, s_want, s_K;
    __shared__ float s_extra;
    __shared__ float redbuf[16];

    if (np > 0) {
        int l = li >> 5, b = li & 31;
        int HW, keyofs;
        if (l == 0)      { HW = 16384; keyofs = KEY_OFS0; }
        else if (l == 1) { HW = 4096;  keyofs = KEY_OFS1; }
        else             { HW = 1024;  keyofs = KEY_OFS2; }
        int N  = HW * 3;
        int N4 = N >> 2;
        const uint4* kk4 = reinterpret_cast<const uint4*>(keys + keyofs + (size_t)b * N);

        unsigned prefix = 0;
        int K = 0, want = 0;
        float negsum = 0.f;
        int lane = t & 63;

        for (int pass = 0; pass < 4; ++pass) {
            if (t < 256) { lhist[t] = 0; lsumf[t] = 0.f; }
            __syncthreads();

            float big = 0.f;
            if (pass == 0) {
                for (int i = t; i < N4; i += 1024) {
                    uint4 k4 = kk4[i];
                    atomicAdd(&lhist[k4.x >> 24], 1);
                    atomicAdd(&lhist[k4.y >> 24], 1);
                    atomicAdd(&lhist[k4.z >> 24], 1);
                    atomicAdd(&lhist[k4.w >> 24], 1);
                }
            } else if (pass < 3) {
                int shift = 24 - 8 * pass;
                for (int i = t; i < N4; i += 1024) {
                    uint4 k4 = kk4[i];
                    unsigned kA[4] = {k4.x, k4.y, k4.z, k4.w};
                    #pragma unroll
                    for (int j = 0; j < 4; ++j)
                        if ((kA[j] >> (shift + 8)) == prefix)
                            atomicAdd(&lhist[(kA[j] >> shift) & 255u], 1);
                }
            } else {
                for (int i = t; i < N4; i += 1024) {
                    uint4 k4 = kk4[i];
                    unsigned kA[4] = {k4.x, k4.y, k4.z, k4.w};
                    #pragma unroll
                    for (int j = 0; j < 4; ++j) {
                        unsigned key = kA[j];
                        unsigned top = key >> 8;
                        if (top > prefix) big += unmapf(key);
                        else if (top == prefix) {
                            atomicAdd(&lhist[key & 255u], 1);
                            atomicAdd(&lsumf[key & 255u], unmapf(key));
                        }
                    }
                }
                for (int off = 32; off > 0; off >>= 1) big += __shfl_down(big, off, 64);
                if (lane == 0) redbuf[t >> 6] = big;
            }
            __syncthreads();
            if (pass == 3 && t == 0) {
                float sb = 0.f;
                for (int j = 0; j < 16; ++j) sb += redbuf[j];
                s_extra = sb;
            }

            // suffix scan of lhist (and lsumf on pass 3) using threads 0..255
            int v = 0; float vf = 0.f;
            if (t < 256) {
                v = lhist[t]; vf = lsumf[t];
                for (int off = 1; off < 64; off <<= 1) {
                    int   o  = __shfl_down(v,  off, 64);
                    float of = __shfl_down(vf, off, 64);
                    if (lane + off < 64) { v += o; vf += of; }
                }
                if (lane == 0) { wtot[t >> 6] = v; wtotf[t >> 6] = vf; }
            }
            __syncthreads();
            if (t < 256) {
                int w = t >> 6;
                int add = 0; float addf = 0.f;
                for (int j = w + 1; j < 4; ++j) { add += wtot[j]; addf += wtotf[j]; }
                sufi[t] = v + add;
                suff[t] = vf + addf;
            }
            if (t == 0) { sufi[256] = 0; suff[256] = 0.f; }
            __syncthreads();

            if (pass == 0) {
                if (t == 0) s_K = min(3 * np, sufi[128]);
                __syncthreads();
                K = s_K; want = K;
                if (K == 0) break;
            }
            if (t < 256 && sufi[t] >= want && sufi[t + 1] < want) {
                s_bin  = t;
                s_want = want - sufi[t + 1];
            }
            __syncthreads();
            prefix = (prefix << 8) | (unsigned)s_bin;
            want   = s_want;
            __syncthreads();
        }

        if (t == 0) {
            if (K > 0) {
                int b0 = (int)(prefix & 255u);
                negsum = s_extra + suff[b0 + 1] + (float)want * unmapf(prefix);
            }
            int nsel = np + K;
            float obj_l = (sumbce[li] + negsum) / (float)nsel;
            float cls_l = sumce[li] / (float)np;
            float loc_l = sumsl1[li] / (float)(4 * np);
            atomicAdd(&tot[0], obj_l);
            atomicAdd(&tot[1], cls_l);
            atomicAdd(&tot[2], loc_l);
        }
    }

    // fused finalize: last block to arrive writes the output
    __threadfence();
    if (t == 0) {
        int prev = atomicAdd(dcount, 1);
        if (prev == 95) {
            __threadfence();
            float o  = atomicAdd(&tot[0], 0.f) * (1.f / BATCH);
            float c  = atomicAdd(&tot[1], 0.f) * (1.f / BATCH);
            float lo = atomicAdd(&tot[2], 0.f) * (1.f / BATCH);
            out[0] = o; out[1] = c; out[2] = lo; out[3] = o + c + 2.f * lo;
        }
    }
}

extern "C" void kernel_launch(void* const* d_in, const int* in_sizes, int n_in,
                              void* d_out, int out_size, void* d_ws, size_t ws_size,
                              hipStream_t stream) {
    const float* pred0   = (const float*)d_in[0];
    const float* pred1   = (const float*)d_in[1];
    const float* pred2   = (const float*)d_in[2];
    const float* tboxes  = (const float*)d_in[6];
    const int*   tlabels = (const int*)d_in[7];

    char* ws = (char*)d_ws;
    int*      nposA  = (int*)ws;
    float*    sumbce = (float*)(ws + 1024);
    float*    sumce  = (float*)(ws + 2048);
    float*    sumsl1 = (float*)(ws + 3072);
    float*    tot    = (float*)(ws + 4096);
    int*      dcount = (int*)(ws + 4112);
    unsigned* keys   = (unsigned*)(ws + 8192);

    hipLaunchKernelGGL(k_init, dim3(1), dim3(1024), 0, stream, (int*)ws);
    hipLaunchKernelGGL(k_assign, dim3(2688), dim3(256), 0, stream,
                       pred0, pred1, pred2, tboxes, tlabels,
                       nposA, sumbce, sumce, sumsl1, keys);
    hipLaunchKernelGGL(k_select, dim3(96), dim3(1024), 0, stream,
                       nposA, sumbce, sumce, sumsl1, keys, tot, dcount,
                       (float*)d_out);
}